// Round 4
// baseline (523.278 us; speedup 1.0000x reference)
//
#include <hip/hip_runtime.h>

using u16 = unsigned short;
typedef __bf16 bf16x8 __attribute__((ext_vector_type(8)));
typedef float floatx4 __attribute__((ext_vector_type(4)));

// ---------- helpers ----------
__device__ __forceinline__ u16 f2bf(float f) {
    union { float f; unsigned u; } v; v.f = f;
    unsigned r = v.u + 0x7fffu + ((v.u >> 16) & 1u);   // RNE
    return (u16)(r >> 16);
}

__device__ __forceinline__ void gld16(const void* g, void* l) {
    __builtin_amdgcn_global_load_lds(
        (const __attribute__((address_space(1))) void*)g,
        (__attribute__((address_space(3))) void*)l, 16, 0, 0);
}

__device__ __forceinline__ void cvt4(const float* __restrict__ src,
                                     u16* __restrict__ dst, int i) {
    float4 v = *(const float4*)(src + i);
    ushort4 o;
    o.x = f2bf(v.x); o.y = f2bf(v.y); o.z = f2bf(v.z); o.w = f2bf(v.w);
    *(ushort4*)(dst + i) = o;
}

// ---------- prep: converts + time-qkv + bias expansion ----------
// blocks: [0,768) Wqkv cvt | [768,1024) Wo cvt | [1024,1120) time qkv |
//         [1120,1152) bias_full | [1152,9344) x cvt
__global__ __launch_bounds__(256) void prep_k(
    const float* __restrict__ x, const float* __restrict__ Wqkv,
    const float* __restrict__ Wo, const float* __restrict__ te,
    const float* __restrict__ Wt, const float* __restrict__ bt,
    const float* __restrict__ btab,
    u16* __restrict__ xbf, u16* __restrict__ wqkvbf, u16* __restrict__ wobf,
    float* __restrict__ qkvt, float* __restrict__ biasf)
{
    const int b = blockIdx.x, tid = threadIdx.x;
    if (b < 768) {
        cvt4(Wqkv, wqkvbf, b * 1024 + tid * 4);
    } else if (b < 1024) {
        cvt4(Wo, wobf, (b - 768) * 1024 + tid * 4);
    } else if (b < 1120) {
        const int bb = b - 1024;
        const int batch = bb / 6;
        const int c = (bb % 6) * 256 + tid;
        const float4* a4 = (const float4*)(te + batch * 512);
        const float4* w4 = (const float4*)(Wt + (size_t)c * 512);
        float s = 0.f;
        for (int i = 0; i < 128; ++i) {
            float4 av = a4[i], wv = w4[i];
            s += av.x * wv.x + av.y * wv.y + av.z * wv.z + av.w * wv.w;
        }
        qkvt[batch * 1536 + c] = s + bt[c];
    } else if (b < 1152) {
        const int e0 = (b - 1120) * 1024 + tid;
        for (int k = 0; k < 4; ++k) {
            int e = e0 + k * 256;
            int h = e >> 12, rc = e & 4095, row = rc >> 6, col = rc & 63;
            int idx = ((row >> 3) - (col >> 3) + 7) * 15 + ((row & 7) - (col & 7) + 7);
            biasf[e] = btab[idx * 8 + h];
        }
    } else {
        const int base = (b - 1152) * 4096 + tid * 4;
        for (int k = 0; k < 4; ++k) cvt4(x, xbf, base + k * 1024);
    }
}

// ---------- GEMM1: qkv = x @ Wqkv^T + bqkv + qkv_t[batch], bf16 out ----------
// 128x128 tile, BK=32, 4 waves of 64x64 (round-0 proven structure) +
// bijective XCD-chunked swizzle: each XCD owns a contiguous tm-range so
// A is fetched once per XCD and the 1.5 MB B panel set stays L2-resident.
__global__ __launch_bounds__(256, 3) void gemm_qkv_k(
    const u16* __restrict__ A, const u16* __restrict__ B,
    const float* __restrict__ bqkv, const float* __restrict__ qkvt,
    u16* __restrict__ C)
{
    __shared__ __align__(16) u16 lA[128 * 32];
    __shared__ __align__(16) u16 lB[128 * 32];
    const int tid = threadIdx.x;
    const int lane = tid & 63, wv = tid >> 6;
    const int ln = lane & 15, quad = lane >> 4;

    // XCD swizzle over 6144 blocks (6144 % 8 == 0 -> bijective)
    const int orig = blockIdx.y * 12 + blockIdx.x;
    const int wgid = (orig & 7) * 768 + (orig >> 3);
    const int tm = wgid / 12, tn = wgid % 12;

    const int wm = (wv & 1) * 64, wn = (wv >> 1) * 64;

    floatx4 acc[4][4];
#pragma unroll
    for (int i = 0; i < 4; ++i)
#pragma unroll
        for (int j = 0; j < 4; ++j) acc[i][j] = (floatx4){0.f, 0.f, 0.f, 0.f};

    const int srow = tid >> 2, scb = tid & 3;
    const u16* ag = A + (size_t)(tm * 128 + srow) * 512 + scb * 8;
    const u16* bg = B + (size_t)(tn * 128 + srow) * 512 + scb * 8;
    u16* la0 = &lA[tid * 8];
    u16* la1 = &lA[2048 + tid * 8];
    u16* lb0 = &lB[tid * 8];
    u16* lb1 = &lB[2048 + tid * 8];

    for (int k0 = 0; k0 < 512; k0 += 32) {
        __syncthreads();
        gld16(ag + k0, la0);
        gld16(ag + 64 * 512 + k0, la1);
        gld16(bg + k0, lb0);
        gld16(bg + 64 * 512 + k0, lb1);
        __syncthreads();          // drains vmcnt: LDS tiles ready
        bf16x8 af[4], bf[4];
#pragma unroll
        for (int mt = 0; mt < 4; ++mt)
            af[mt] = *(const bf16x8*)&lA[(wm + mt * 16 + ln) * 32 + quad * 8];
#pragma unroll
        for (int nt = 0; nt < 4; ++nt)
            bf[nt] = *(const bf16x8*)&lB[(wn + nt * 16 + ln) * 32 + quad * 8];
#pragma unroll
        for (int mt = 0; mt < 4; ++mt)
#pragma unroll
            for (int nt = 0; nt < 4; ++nt)
                acc[mt][nt] = __builtin_amdgcn_mfma_f32_16x16x32_bf16(
                    af[mt], bf[nt], acc[mt][nt], 0, 0, 0);
    }

    const float* qt = qkvt + (tm >> 5) * 1536;   // batch uniform per 128-row tile
#pragma unroll
    for (int nt = 0; nt < 4; ++nt) {
        const int col = tn * 128 + wn + nt * 16 + ln;
        const float add = bqkv[col] + qt[col];
#pragma unroll
        for (int mt = 0; mt < 4; ++mt) {
            const int row0 = tm * 128 + wm + mt * 16 + quad * 4;
#pragma unroll
            for (int r = 0; r < 4; ++r)
                C[(size_t)(row0 + r) * 1536 + col] = f2bf(acc[mt][nt][r] + add);
        }
    }
}

// ---------- attention + output projection: block = 1 window, 8 waves = 8 heads ----------
// Attention per wave exactly as the round-0 proven attn_k (single per-wave LDS
// buf: V^T staged, vtf frags hoisted to regs, then P overwrites the buf).
// Each wave writes its head's O (64x64) into a shared [64][520] LDS attn tile;
// one barrier; then the block computes out = attn @ Wo^T + bo cooperatively
// (wave wv owns 64 output cols), B-frags straight from L2-resident wobf.
__global__ __launch_bounds__(512, 1) void attn_out_k(
    const u16* __restrict__ qkv, const float* __restrict__ biasf,
    const u16* __restrict__ wo, const float* __restrict__ bo,
    float* __restrict__ out)
{
    __shared__ __align__(16) u16 ab[64 * 520];       // attn rows, 66,560 B
    __shared__ __align__(16) u16 sbuf[8][64 * 72];   // per-wave, 73,728 B
    const int tid = threadIdx.x, lane = tid & 63, wv = tid >> 6;
    const int ln = lane & 15, quad = lane >> 4;
    const int w = blockIdx.x;
    const int bb = w >> 6, nh = (w >> 3) & 7, nw = w & 7;
    const int tbase = bb * 4096 + nh * 512 + nw * 8;  // + wi*64 + wj
    const int h = wv;
    u16* buf = sbuf[wv];

    // ---- V load (coalesced rows) + transpose into buf: [d][n] ----
    {
        const int wj = lane >> 3;           // 0..7
        const int d0 = (lane & 7) * 8;      // 0..56
#pragma unroll
        for (int i = 0; i < 8; ++i) {
            const int t = tbase + i * 64 + wj;     // token of n = i*8+wj
            union { bf16x8 v; u16 u[8]; } cv;
            cv.v = *(const bf16x8*)(qkv + (size_t)t * 1536 + 1024 + h * 64 + d0);
            const int n = i * 8 + wj;
#pragma unroll
            for (int j = 0; j < 8; ++j) buf[(d0 + j) * 72 + n] = cv.u[j];
        }
    }

    // ---- hoist V^T B-frags to regs (before P overwrites buf) ----
    bf16x8 vtf[4][2];
#pragma unroll
    for (int dt = 0; dt < 4; ++dt) {
        const u16* vr = &buf[(dt * 16 + ln) * 72 + quad * 8];
        vtf[dt][0] = *(const bf16x8*)vr;
        vtf[dt][1] = *(const bf16x8*)(vr + 32);
    }

    // ---- K fragments (B-operand layout, straight from global) ----
    bf16x8 kf[4][2];
#pragma unroll
    for (int nt = 0; nt < 4; ++nt) {
        const int n = nt * 16 + ln;
        const int t = tbase + (n >> 3) * 64 + (n & 7);
        const u16* kr = qkv + (size_t)t * 1536 + 512 + h * 64 + quad * 8;
        kf[nt][0] = *(const bf16x8*)kr;
        kf[nt][1] = *(const bf16x8*)(kr + 32);
    }

    // ---- S = Q K^T * scale + bias, softmax, P -> buf (bf16) ----
#pragma unroll
    for (int mt = 0; mt < 4; ++mt) {
        const int m = mt * 16 + ln;
        const int t = tbase + (m >> 3) * 64 + (m & 7);
        const u16* qr = qkv + (size_t)t * 1536 + h * 64 + quad * 8;
        const bf16x8 qf0 = *(const bf16x8*)qr;
        const bf16x8 qf1 = *(const bf16x8*)(qr + 32);
        floatx4 s[4];
        __builtin_amdgcn_s_setprio(1);
#pragma unroll
        for (int nt = 0; nt < 4; ++nt) {
            s[nt] = (floatx4){0.f, 0.f, 0.f, 0.f};
            s[nt] = __builtin_amdgcn_mfma_f32_16x16x32_bf16(qf0, kf[nt][0], s[nt], 0, 0, 0);
            s[nt] = __builtin_amdgcn_mfma_f32_16x16x32_bf16(qf1, kf[nt][1], s[nt], 0, 0, 0);
        }
        __builtin_amdgcn_s_setprio(0);
        float z[4][4];
        const float* bptr = biasf + h * 4096 + (mt * 16 + quad * 4) * 64 + ln;
#pragma unroll
        for (int nt = 0; nt < 4; ++nt)
#pragma unroll
            for (int r = 0; r < 4; ++r)
                z[nt][r] = s[nt][r] * 0.125f + bptr[r * 64 + nt * 16];
        float pmax[4], prcp[4];
#pragma unroll
        for (int r = 0; r < 4; ++r) {
            float v = fmaxf(fmaxf(z[0][r], z[1][r]), fmaxf(z[2][r], z[3][r]));
            v = fmaxf(v, __shfl_xor(v, 1));
            v = fmaxf(v, __shfl_xor(v, 2));
            v = fmaxf(v, __shfl_xor(v, 4));
            v = fmaxf(v, __shfl_xor(v, 8));
            pmax[r] = v;
        }
#pragma unroll
        for (int nt = 0; nt < 4; ++nt)
#pragma unroll
            for (int r = 0; r < 4; ++r)
                z[nt][r] = __expf(z[nt][r] - pmax[r]);
#pragma unroll
        for (int r = 0; r < 4; ++r) {
            float v = z[0][r] + z[1][r] + z[2][r] + z[3][r];
            v += __shfl_xor(v, 1);
            v += __shfl_xor(v, 2);
            v += __shfl_xor(v, 4);
            v += __shfl_xor(v, 8);
            prcp[r] = __builtin_amdgcn_rcpf(v);
        }
#pragma unroll
        for (int nt = 0; nt < 4; ++nt)
#pragma unroll
            for (int r = 0; r < 4; ++r)
                buf[(mt * 16 + quad * 4 + r) * 72 + nt * 16 + ln] =
                    f2bf(z[nt][r] * prcp[r]);
    }

    // ---- O = P @ V -> shared attn tile ab[64][520] ----
#pragma unroll
    for (int mt = 0; mt < 4; ++mt) {
        const u16* pr = &buf[(mt * 16 + ln) * 72 + quad * 8];
        const bf16x8 pf0 = *(const bf16x8*)pr;
        const bf16x8 pf1 = *(const bf16x8*)(pr + 32);
#pragma unroll
        for (int dt = 0; dt < 4; ++dt) {
            floatx4 o = (floatx4){0.f, 0.f, 0.f, 0.f};
            __builtin_amdgcn_s_setprio(1);
            o = __builtin_amdgcn_mfma_f32_16x16x32_bf16(pf0, vtf[dt][0], o, 0, 0, 0);
            o = __builtin_amdgcn_mfma_f32_16x16x32_bf16(pf1, vtf[dt][1], o, 0, 0, 0);
            __builtin_amdgcn_s_setprio(0);
#pragma unroll
            for (int r = 0; r < 4; ++r)
                ab[(mt * 16 + quad * 4 + r) * 520 + h * 64 + dt * 16 + ln] =
                    f2bf(o[r]);
        }
    }

    __syncthreads();   // all heads' O in ab

    // ---- out = ab @ Wo^T + bo : wave wv owns cols wv*64..+64 ----
    floatx4 acc[4][4];
#pragma unroll
    for (int i = 0; i < 4; ++i)
#pragma unroll
        for (int j = 0; j < 4; ++j) acc[i][j] = (floatx4){0.f, 0.f, 0.f, 0.f};
    const u16* wb = wo + (size_t)(wv * 64 + ln) * 512 + quad * 8;

    bf16x8 aX[4], bX[4], aY[4], bY[4];
#pragma unroll
    for (int mt = 0; mt < 4; ++mt)
        aX[mt] = *(const bf16x8*)&ab[(mt * 16 + ln) * 520 + quad * 8];
#pragma unroll
    for (int nt = 0; nt < 4; ++nt)
        bX[nt] = *(const bf16x8*)(wb + (size_t)nt * 16 * 512);

#pragma unroll
    for (int ks = 0; ks < 16; ks += 2) {
        if (ks + 1 < 16) {
#pragma unroll
            for (int mt = 0; mt < 4; ++mt)
                aY[mt] = *(const bf16x8*)&ab[(mt * 16 + ln) * 520 + (ks + 1) * 32 + quad * 8];
#pragma unroll
            for (int nt = 0; nt < 4; ++nt)
                bY[nt] = *(const bf16x8*)(wb + (size_t)nt * 16 * 512 + (ks + 1) * 32);
        }
        __builtin_amdgcn_s_setprio(1);
#pragma unroll
        for (int mt = 0; mt < 4; ++mt)
#pragma unroll
            for (int nt = 0; nt < 4; ++nt)
                acc[mt][nt] = __builtin_amdgcn_mfma_f32_16x16x32_bf16(
                    aX[mt], bX[nt], acc[mt][nt], 0, 0, 0);
        __builtin_amdgcn_s_setprio(0);
        if (ks + 2 < 16) {
#pragma unroll
            for (int mt = 0; mt < 4; ++mt)
                aX[mt] = *(const bf16x8*)&ab[(mt * 16 + ln) * 520 + (ks + 2) * 32 + quad * 8];
#pragma unroll
            for (int nt = 0; nt < 4; ++nt)
                bX[nt] = *(const bf16x8*)(wb + (size_t)nt * 16 * 512 + (ks + 2) * 32);
        }
        __builtin_amdgcn_s_setprio(1);
#pragma unroll
        for (int mt = 0; mt < 4; ++mt)
#pragma unroll
            for (int nt = 0; nt < 4; ++nt)
                acc[mt][nt] = __builtin_amdgcn_mfma_f32_16x16x32_bf16(
                    aY[mt], bY[nt], acc[mt][nt], 0, 0, 0);
        __builtin_amdgcn_s_setprio(0);
    }

#pragma unroll
    for (int nt = 0; nt < 4; ++nt) {
        const int col = wv * 64 + nt * 16 + ln;
        const float add = bo[col];
#pragma unroll
        for (int mt = 0; mt < 4; ++mt) {
            const int row0 = w * 64 + mt * 16 + quad * 4;
#pragma unroll
            for (int r = 0; r < 4; ++r)
                out[(size_t)(row0 + r) * 512 + col] = acc[mt][nt][r] + add;
        }
    }
}

// ---------- launch ----------
extern "C" void kernel_launch(void* const* d_in, const int* in_sizes, int n_in,
                              void* d_out, int out_size, void* d_ws, size_t ws_size,
                              hipStream_t stream)
{
    const float* x    = (const float*)d_in[0];
    const float* te   = (const float*)d_in[1];
    const float* Wqkv = (const float*)d_in[2];
    const float* bqkv = (const float*)d_in[3];
    const float* Wt   = (const float*)d_in[4];
    const float* bt   = (const float*)d_in[5];
    const float* Wo   = (const float*)d_in[6];
    const float* bo   = (const float*)d_in[7];
    const float* btab = (const float*)d_in[8];
    float* out = (float*)d_out;

    char* w = (char*)d_ws;
    u16*   xbf    = (u16*)(w);                   // 67,108,864 B
    u16*   qkvbf  = (u16*)(w + 67108864);        // 201,326,592 B
    u16*   wqkvbf = (u16*)(w + 268435456);       // 1,572,864 B
    u16*   wobf   = (u16*)(w + 270008320);       // 524,288 B
    float* qkvt   = (float*)(w + 270532608);     // 98,304 B
    float* biasf  = (float*)(w + 270630912);     // 131,072 B  (total ~258.2 MiB)

    prep_k<<<9344, 256, 0, stream>>>(x, Wqkv, Wo, te, Wt, bt, btab,
                                     xbf, wqkvbf, wobf, qkvt, biasf);
    gemm_qkv_k<<<dim3(12, 512), 256, 0, stream>>>(xbf, wqkvbf, bqkv, qkvt, qkvbf);
    attn_out_k<<<1024, 512, 0, stream>>>(qkvbf, biasf, wobf, bo, out);
}

// Round 5
// 507.094 us; speedup vs baseline: 1.0319x; 1.0319x over previous
//
#include <hip/hip_runtime.h>

using u16 = unsigned short;
typedef __bf16 bf16x8 __attribute__((ext_vector_type(8)));
typedef float floatx4 __attribute__((ext_vector_type(4)));

// ---------- helpers ----------
__device__ __forceinline__ u16 f2bf(float f) {
    union { float f; unsigned u; } v; v.f = f;
    unsigned r = v.u + 0x7fffu + ((v.u >> 16) & 1u);   // RNE
    return (u16)(r >> 16);
}

__device__ __forceinline__ void gld16(const void* g, void* l) {
    __builtin_amdgcn_global_load_lds(
        (const __attribute__((address_space(1))) void*)g,
        (__attribute__((address_space(3))) void*)l, 16, 0, 0);
}

__device__ __forceinline__ void cvt4(const float* __restrict__ src,
                                     u16* __restrict__ dst, int i) {
    float4 v = *(const float4*)(src + i);
    ushort4 o;
    o.x = f2bf(v.x); o.y = f2bf(v.y); o.z = f2bf(v.z); o.w = f2bf(v.w);
    *(ushort4*)(dst + i) = o;
}

// ---------- prep: converts + time-qkv + bias expansion ----------
// blocks: [0,768) Wqkv cvt | [768,1024) Wo cvt | [1024,1120) time qkv |
//         [1120,1152) bias_full | [1152,9344) x cvt
__global__ __launch_bounds__(256) void prep_k(
    const float* __restrict__ x, const float* __restrict__ Wqkv,
    const float* __restrict__ Wo, const float* __restrict__ te,
    const float* __restrict__ Wt, const float* __restrict__ bt,
    const float* __restrict__ btab,
    u16* __restrict__ xbf, u16* __restrict__ wqkvbf, u16* __restrict__ wobf,
    float* __restrict__ qkvt, float* __restrict__ biasf)
{
    const int b = blockIdx.x, tid = threadIdx.x;
    if (b < 768) {
        cvt4(Wqkv, wqkvbf, b * 1024 + tid * 4);
    } else if (b < 1024) {
        cvt4(Wo, wobf, (b - 768) * 1024 + tid * 4);
    } else if (b < 1120) {
        const int bb = b - 1024;
        const int batch = bb / 6;
        const int c = (bb % 6) * 256 + tid;
        const float4* a4 = (const float4*)(te + batch * 512);
        const float4* w4 = (const float4*)(Wt + (size_t)c * 512);
        float s = 0.f;
        for (int i = 0; i < 128; ++i) {
            float4 av = a4[i], wv = w4[i];
            s += av.x * wv.x + av.y * wv.y + av.z * wv.z + av.w * wv.w;
        }
        qkvt[batch * 1536 + c] = s + bt[c];
    } else if (b < 1152) {
        const int e0 = (b - 1120) * 1024 + tid;
        for (int k = 0; k < 4; ++k) {
            int e = e0 + k * 256;
            int h = e >> 12, rc = e & 4095, row = rc >> 6, col = rc & 63;
            int idx = ((row >> 3) - (col >> 3) + 7) * 15 + ((row & 7) - (col & 7) + 7);
            biasf[e] = btab[idx * 8 + h];
        }
    } else {
        const int base = (b - 1152) * 4096 + tid * 4;
        for (int k = 0; k < 4; ++k) cvt4(x, xbf, base + k * 1024);
    }
}

// ---------- GEMM1: qkv = x @ Wqkv^T + bqkv + qkv_t[batch], bf16 out ----------
// 128x128 tile, BK=32, 4 waves of 64x64 (round-0 proven structure) +
// bijective XCD-chunked swizzle (control: unchanged from round 4).
__global__ __launch_bounds__(256, 3) void gemm_qkv_k(
    const u16* __restrict__ A, const u16* __restrict__ B,
    const float* __restrict__ bqkv, const float* __restrict__ qkvt,
    u16* __restrict__ C)
{
    __shared__ __align__(16) u16 lA[128 * 32];
    __shared__ __align__(16) u16 lB[128 * 32];
    const int tid = threadIdx.x;
    const int lane = tid & 63, wv = tid >> 6;
    const int ln = lane & 15, quad = lane >> 4;

    // XCD swizzle over 6144 blocks (6144 % 8 == 0 -> bijective)
    const int orig = blockIdx.y * 12 + blockIdx.x;
    const int wgid = (orig & 7) * 768 + (orig >> 3);
    const int tm = wgid / 12, tn = wgid % 12;

    const int wm = (wv & 1) * 64, wn = (wv >> 1) * 64;

    floatx4 acc[4][4];
#pragma unroll
    for (int i = 0; i < 4; ++i)
#pragma unroll
        for (int j = 0; j < 4; ++j) acc[i][j] = (floatx4){0.f, 0.f, 0.f, 0.f};

    const int srow = tid >> 2, scb = tid & 3;
    const u16* ag = A + (size_t)(tm * 128 + srow) * 512 + scb * 8;
    const u16* bg = B + (size_t)(tn * 128 + srow) * 512 + scb * 8;
    u16* la0 = &lA[tid * 8];
    u16* la1 = &lA[2048 + tid * 8];
    u16* lb0 = &lB[tid * 8];
    u16* lb1 = &lB[2048 + tid * 8];

    for (int k0 = 0; k0 < 512; k0 += 32) {
        __syncthreads();
        gld16(ag + k0, la0);
        gld16(ag + 64 * 512 + k0, la1);
        gld16(bg + k0, lb0);
        gld16(bg + 64 * 512 + k0, lb1);
        __syncthreads();          // drains vmcnt: LDS tiles ready
        bf16x8 af[4], bf[4];
#pragma unroll
        for (int mt = 0; mt < 4; ++mt)
            af[mt] = *(const bf16x8*)&lA[(wm + mt * 16 + ln) * 32 + quad * 8];
#pragma unroll
        for (int nt = 0; nt < 4; ++nt)
            bf[nt] = *(const bf16x8*)&lB[(wn + nt * 16 + ln) * 32 + quad * 8];
#pragma unroll
        for (int mt = 0; mt < 4; ++mt)
#pragma unroll
            for (int nt = 0; nt < 4; ++nt)
                acc[mt][nt] = __builtin_amdgcn_mfma_f32_16x16x32_bf16(
                    af[mt], bf[nt], acc[mt][nt], 0, 0, 0);
    }

    const float* qt = qkvt + (tm >> 5) * 1536;   // batch uniform per 128-row tile
#pragma unroll
    for (int nt = 0; nt < 4; ++nt) {
        const int col = tn * 128 + wn + nt * 16 + ln;
        const float add = bqkv[col] + qt[col];
#pragma unroll
        for (int mt = 0; mt < 4; ++mt) {
            const int row0 = tm * 128 + wm + mt * 16 + quad * 4;
#pragma unroll
            for (int r = 0; r < 4; ++r)
                C[(size_t)(row0 + r) * 1536 + col] = f2bf(acc[mt][nt][r] + add);
        }
    }
}

// ---------- attention: one wave per (window, head), single per-wave buffer ----------
// 36.9 KB LDS -> 4 blocks/CU (vs 147 KB / 1 block in the old two-buffer version).
// No __syncthreads: each wave owns its buffer; V^T frags are hoisted to regs
// before P overwrites the buffer (pattern numerically validated in round 4).
__global__ __launch_bounds__(256, 4) void attn_k(
    const u16* __restrict__ qkv, const float* __restrict__ biasf,
    u16* __restrict__ aout)
{
    __shared__ __align__(16) u16 sbuf[4][64 * 72];   // 36,864 B
    const int tid = threadIdx.x, lane = tid & 63, wv = tid >> 6;
    const int ln = lane & 15, quad = lane >> 4;
    const int pair = blockIdx.x * 4 + wv;
    const int w = pair >> 3, h = pair & 7;
    const int bb = w >> 6, nh = (w >> 3) & 7, nw = w & 7;
    const int tbase = bb * 4096 + nh * 512 + nw * 8;  // + wi*64 + wj
    u16* buf = sbuf[wv];

    // ---- V load (coalesced rows) + transpose into buf: [d][n] ----
    {
        const int wj = lane >> 3;           // 0..7
        const int d0 = (lane & 7) * 8;      // 0..56
#pragma unroll
        for (int i = 0; i < 8; ++i) {
            const int t = tbase + i * 64 + wj;     // token of n = i*8+wj
            union { bf16x8 v; u16 u[8]; } cv;
            cv.v = *(const bf16x8*)(qkv + (size_t)t * 1536 + 1024 + h * 64 + d0);
            const int n = i * 8 + wj;
#pragma unroll
            for (int j = 0; j < 8; ++j) buf[(d0 + j) * 72 + n] = cv.u[j];
        }
    }

    // ---- hoist V^T B-frags to regs (before P overwrites buf) ----
    bf16x8 vtf[4][2];
#pragma unroll
    for (int dt = 0; dt < 4; ++dt) {
        const u16* vr = &buf[(dt * 16 + ln) * 72 + quad * 8];
        vtf[dt][0] = *(const bf16x8*)vr;
        vtf[dt][1] = *(const bf16x8*)(vr + 32);
    }

    // ---- K fragments (B-operand layout, straight from global) ----
    bf16x8 kf[4][2];
#pragma unroll
    for (int nt = 0; nt < 4; ++nt) {
        const int n = nt * 16 + ln;
        const int t = tbase + (n >> 3) * 64 + (n & 7);
        const u16* kr = qkv + (size_t)t * 1536 + 512 + h * 64 + quad * 8;
        kf[nt][0] = *(const bf16x8*)kr;
        kf[nt][1] = *(const bf16x8*)(kr + 32);
    }

    // ---- S = Q K^T * scale + bias, softmax, P -> buf (bf16) ----
#pragma unroll
    for (int mt = 0; mt < 4; ++mt) {
        const int m = mt * 16 + ln;
        const int t = tbase + (m >> 3) * 64 + (m & 7);
        const u16* qr = qkv + (size_t)t * 1536 + h * 64 + quad * 8;
        const bf16x8 qf0 = *(const bf16x8*)qr;
        const bf16x8 qf1 = *(const bf16x8*)(qr + 32);
        floatx4 s[4];
        __builtin_amdgcn_s_setprio(1);
#pragma unroll
        for (int nt = 0; nt < 4; ++nt) {
            s[nt] = (floatx4){0.f, 0.f, 0.f, 0.f};
            s[nt] = __builtin_amdgcn_mfma_f32_16x16x32_bf16(qf0, kf[nt][0], s[nt], 0, 0, 0);
            s[nt] = __builtin_amdgcn_mfma_f32_16x16x32_bf16(qf1, kf[nt][1], s[nt], 0, 0, 0);
        }
        __builtin_amdgcn_s_setprio(0);
        float z[4][4];
        const float* bptr = biasf + h * 4096 + (mt * 16 + quad * 4) * 64 + ln;
#pragma unroll
        for (int nt = 0; nt < 4; ++nt)
#pragma unroll
            for (int r = 0; r < 4; ++r)
                z[nt][r] = s[nt][r] * 0.125f + bptr[r * 64 + nt * 16];
        float pmax[4], prcp[4];
#pragma unroll
        for (int r = 0; r < 4; ++r) {
            float v = fmaxf(fmaxf(z[0][r], z[1][r]), fmaxf(z[2][r], z[3][r]));
            v = fmaxf(v, __shfl_xor(v, 1));
            v = fmaxf(v, __shfl_xor(v, 2));
            v = fmaxf(v, __shfl_xor(v, 4));
            v = fmaxf(v, __shfl_xor(v, 8));
            pmax[r] = v;
        }
#pragma unroll
        for (int nt = 0; nt < 4; ++nt)
#pragma unroll
            for (int r = 0; r < 4; ++r)
                z[nt][r] = __expf(z[nt][r] - pmax[r]);
#pragma unroll
        for (int r = 0; r < 4; ++r) {
            float v = z[0][r] + z[1][r] + z[2][r] + z[3][r];
            v += __shfl_xor(v, 1);
            v += __shfl_xor(v, 2);
            v += __shfl_xor(v, 4);
            v += __shfl_xor(v, 8);
            prcp[r] = __builtin_amdgcn_rcpf(v);
        }
#pragma unroll
        for (int nt = 0; nt < 4; ++nt)
#pragma unroll
            for (int r = 0; r < 4; ++r)
                buf[(mt * 16 + quad * 4 + r) * 72 + nt * 16 + ln] =
                    f2bf(z[nt][r] * prcp[r]);
    }

    // ---- O = P @ V : A-op from buf (P), B-op from vtf regs ----
#pragma unroll
    for (int mt = 0; mt < 4; ++mt) {
        const u16* pr = &buf[(mt * 16 + ln) * 72 + quad * 8];
        const bf16x8 pf0 = *(const bf16x8*)pr;
        const bf16x8 pf1 = *(const bf16x8*)(pr + 32);
#pragma unroll
        for (int dt = 0; dt < 4; ++dt) {
            floatx4 o = (floatx4){0.f, 0.f, 0.f, 0.f};
            __builtin_amdgcn_s_setprio(1);
            o = __builtin_amdgcn_mfma_f32_16x16x32_bf16(pf0, vtf[dt][0], o, 0, 0, 0);
            o = __builtin_amdgcn_mfma_f32_16x16x32_bf16(pf1, vtf[dt][1], o, 0, 0, 0);
            __builtin_amdgcn_s_setprio(0);
            const size_t rbase =
                (size_t)(w * 64 + mt * 16 + quad * 4) * 512 + h * 64 + dt * 16 + ln;
#pragma unroll
            for (int r = 0; r < 4; ++r)
                aout[rbase + (size_t)r * 512] = f2bf(o[r]);
        }
    }
}

// ---------- GEMM2: out = attn @ Wo^T + bo, fp32 out ----------
__global__ __launch_bounds__(256, 3) void gemm_out_k(
    const u16* __restrict__ A, const u16* __restrict__ B,
    const float* __restrict__ bo, float* __restrict__ C)
{
    __shared__ __align__(16) u16 lA[128 * 32];
    __shared__ __align__(16) u16 lB[128 * 32];
    const int tid = threadIdx.x;
    const int lane = tid & 63, wv = tid >> 6;
    const int ln = lane & 15, quad = lane >> 4;

    // XCD swizzle over 2048 blocks (2048 % 8 == 0 -> bijective)
    const int orig = blockIdx.y * 4 + blockIdx.x;
    const int wgid = (orig & 7) * 256 + (orig >> 3);
    const int tm = wgid >> 2, tn = wgid & 3;

    const int wm = (wv & 1) * 64, wn = (wv >> 1) * 64;

    floatx4 acc[4][4];
#pragma unroll
    for (int i = 0; i < 4; ++i)
#pragma unroll
        for (int j = 0; j < 4; ++j) acc[i][j] = (floatx4){0.f, 0.f, 0.f, 0.f};

    const int srow = tid >> 2, scb = tid & 3;
    const u16* ag = A + (size_t)(tm * 128 + srow) * 512 + scb * 8;
    const u16* bg = B + (size_t)(tn * 128 + srow) * 512 + scb * 8;
    u16* la0 = &lA[tid * 8];
    u16* la1 = &lA[2048 + tid * 8];
    u16* lb0 = &lB[tid * 8];
    u16* lb1 = &lB[2048 + tid * 8];

    for (int k0 = 0; k0 < 512; k0 += 32) {
        __syncthreads();
        gld16(ag + k0, la0);
        gld16(ag + 64 * 512 + k0, la1);
        gld16(bg + k0, lb0);
        gld16(bg + 64 * 512 + k0, lb1);
        __syncthreads();
        bf16x8 af[4], bf[4];
#pragma unroll
        for (int mt = 0; mt < 4; ++mt)
            af[mt] = *(const bf16x8*)&lA[(wm + mt * 16 + ln) * 32 + quad * 8];
#pragma unroll
        for (int nt = 0; nt < 4; ++nt)
            bf[nt] = *(const bf16x8*)&lB[(wn + nt * 16 + ln) * 32 + quad * 8];
#pragma unroll
        for (int mt = 0; mt < 4; ++mt)
#pragma unroll
            for (int nt = 0; nt < 4; ++nt)
                acc[mt][nt] = __builtin_amdgcn_mfma_f32_16x16x32_bf16(
                    af[mt], bf[nt], acc[mt][nt], 0, 0, 0);
    }

#pragma unroll
    for (int nt = 0; nt < 4; ++nt) {
        const int col = tn * 128 + wn + nt * 16 + ln;
        const float add = bo[col];
#pragma unroll
        for (int mt = 0; mt < 4; ++mt) {
            const int row0 = tm * 128 + wm + mt * 16 + quad * 4;
#pragma unroll
            for (int r = 0; r < 4; ++r)
                C[(size_t)(row0 + r) * 512 + col] = acc[mt][nt][r] + add;
        }
    }
}

// ---------- launch ----------
extern "C" void kernel_launch(void* const* d_in, const int* in_sizes, int n_in,
                              void* d_out, int out_size, void* d_ws, size_t ws_size,
                              hipStream_t stream)
{
    const float* x    = (const float*)d_in[0];
    const float* te   = (const float*)d_in[1];
    const float* Wqkv = (const float*)d_in[2];
    const float* bqkv = (const float*)d_in[3];
    const float* Wt   = (const float*)d_in[4];
    const float* bt   = (const float*)d_in[5];
    const float* Wo   = (const float*)d_in[6];
    const float* bo   = (const float*)d_in[7];
    const float* btab = (const float*)d_in[8];
    float* out = (float*)d_out;

    char* w = (char*)d_ws;
    // x_bf (later reused as attn_out): 67,108,864 B
    u16*   xbf    = (u16*)(w);
    u16*   qkvbf  = (u16*)(w + 67108864);        // 201,326,592 B
    u16*   wqkvbf = (u16*)(w + 268435456);       // 1,572,864 B
    u16*   wobf   = (u16*)(w + 270008320);       // 524,288 B
    float* qkvt   = (float*)(w + 270532608);     // 98,304 B
    float* biasf  = (float*)(w + 270630912);     // 131,072 B  (total ~258.2 MiB)

    prep_k<<<9344, 256, 0, stream>>>(x, Wqkv, Wo, te, Wt, bt, btab,
                                     xbf, wqkvbf, wobf, qkvt, biasf);
    gemm_qkv_k<<<dim3(12, 512), 256, 0, stream>>>(xbf, wqkvbf, bqkv, qkvt, qkvbf);
    attn_k<<<2048, 256, 0, stream>>>(qkvbf, biasf, xbf /* reuse as attn_out */);
    gemm_out_k<<<dim3(4, 512), 256, 0, stream>>>(xbf, wobf, bo, out);
}